// Round 2
// baseline (685.513 us; speedup 1.0000x reference)
//
#include <hip/hip_runtime.h>
#include <math.h>

#define NCLS 19      // known classes (void = 19 dropped)
#define NF   256     // feature length
#define HW   16384   // 128*128
#define ROWW 128     // w extent
#define PAD  257     // LDS stride pad (257%32==1 -> distinct labels hit distinct banks)

__global__ __launch_bounds__(256) void zero_protos(float* __restrict__ g) {
    int i = blockIdx.x * 256 + threadIdx.x;
    if (i < NCLS * NF) g[i] = 0.f;
}

// grid 512, block 256. Each block: 4 rows (b,h); each thread: 2 adjacent pixels (float2).
__global__ __launch_bounds__(256) void accum_protos(const float* __restrict__ feat,
                                                    const int* __restrict__ labels,
                                                    float* __restrict__ gproto) {
    __shared__ float lds[NCLS * PAD];   // 19*257 = 4883 floats = 19.5 KB
    for (int i = threadIdx.x; i < NCLS * PAD; i += 256) lds[i] = 0.f;
    __syncthreads();

    const int tid = threadIdx.x;
    const int r   = tid >> 6;            // 0..3 : row within block
    const int w0  = (tid & 63) * 2;      // pixel pair
    const int row = blockIdx.x * 4 + r;  // 0..2047 == b*128 + h
    const int b   = row >> 7;
    const int h   = row & 127;

    const int2 lab = *(const int2*)(labels + row * ROWW + w0);
    const bool a0 = (lab.x < NCLS);
    const bool a1 = (lab.y < NCLS);

    if (a0 | a1) {
        // base element for (b, f=0, h, w0); channel stride = HW floats = 8192 float2
        const float2* p = (const float2*)(feat + ((size_t)b * NF * HW + (size_t)h * ROWW + w0));

        float s0 = 0.f, s1 = 0.f;
        #pragma unroll 8
        for (int f = 0; f < NF; ++f) {
            float2 v = p[(size_t)f * (HW / 2)];
            s0 += v.x * v.x;
            s1 += v.y * v.y;
        }
        const float r0 = a0 ? (1.f / fmaxf(sqrtf(s0), 1e-12f)) : 0.f;
        const float r1 = a1 ? (1.f / fmaxf(sqrtf(s1), 1e-12f)) : 0.f;
        const int  o0 = lab.x * PAD;
        const int  o1 = lab.y * PAD;

        #pragma unroll 8
        for (int f = 0; f < NF; ++f) {
            float2 v = p[(size_t)f * (HW / 2)];   // re-read: block footprint 512KB, cache-resident
            if (a0) atomicAdd(&lds[o0 + f], v.x * r0);
            if (a1) atomicAdd(&lds[o1 + f], v.y * r1);
        }
    }
    __syncthreads();

    // flush block-local prototypes to global accumulator
    for (int i = threadIdx.x; i < NCLS * NF; i += 256) {
        const int c = i >> 8;        // i / 256
        const int f = i & 255;       // i % 256
        const float v = lds[c * PAD + f];
        if (v != 0.f) atomicAdd(&gproto[i], v);
    }
}

// grid 19, block 256. Block c: normalize prototype column c, write transposed out[f*19+c].
__global__ __launch_bounds__(256) void normalize_protos(const float* __restrict__ gproto,
                                                        float* __restrict__ out) {
    __shared__ float ws[4];
    const int c = blockIdx.x;
    const int f = threadIdx.x;
    const float v = gproto[c * NF + f];

    float s = v * v;
    #pragma unroll
    for (int off = 32; off > 0; off >>= 1) s += __shfl_down(s, off, 64);
    if ((f & 63) == 0) ws[f >> 6] = s;
    __syncthreads();
    const float tot = ws[0] + ws[1] + ws[2] + ws[3];
    const float rn = 1.f / fmaxf(sqrtf(tot), 1e-12f);
    out[f * NCLS + c] = v * rn;
}

extern "C" void kernel_launch(void* const* d_in, const int* in_sizes, int n_in,
                              void* d_out, int out_size, void* d_ws, size_t ws_size,
                              hipStream_t stream) {
    const float* feat   = (const float*)d_in[0];
    const int*   labels = (const int*)d_in[1];
    float* out    = (float*)d_out;
    float* gproto = (float*)d_ws;    // NCLS*NF = 4864 floats

    zero_protos<<<NCLS, 256, 0, stream>>>(gproto);              // 19*256 == 4864
    accum_protos<<<512, 256, 0, stream>>>(feat, labels, gproto);
    normalize_protos<<<NCLS, 256, 0, stream>>>(gproto, out);
}